// Round 5
// baseline (4916.091 us; speedup 1.0000x reference)
//
#include <hip/hip_runtime.h>

// Problem constants: T=128, B=128, S=128, H=1024, E=512, V=32000, L=2
#define TT 128
#define BB 128
#define SS 128
#define HH 1024
#define EE 512
#define BH (BB*HH)   // 131072

typedef unsigned short u16;                                   // bf16 bits
typedef __attribute__((ext_vector_type(8))) short s8v;        // MFMA A/B fragment (8 bf16)
typedef __attribute__((ext_vector_type(4))) float f32x4;      // MFMA C/D fragment

__device__ __forceinline__ float b2f(u16 u) {
    union { unsigned int i; float f; } v; v.i = ((unsigned int)u) << 16; return v.f;
}
__device__ __forceinline__ u16 f2b(float f) {
    union { float f; unsigned int i; } v; v.f = f;
    unsigned int x = v.i;
    x = x + 0x7fffu + ((x >> 16) & 1u);   // round-to-nearest-even
    return (u16)(x >> 16);
}
__device__ __forceinline__ float sigm(float x) {
    float t = __expf(-fabsf(x));
    float p = 1.0f / (1.0f + t);
    return x >= 0.0f ? p : 1.0f - p;
}
__device__ __forceinline__ float tanh_(float x) {
    float t = __expf(-2.0f * fabsf(x));
    float r = (1.0f - t) / (1.0f + t);
    return x >= 0.0f ? r : -r;
}

#define MFMA(a, b, c) __builtin_amdgcn_mfma_f32_16x16x32_bf16((a), (b), (c), 0, 0, 0)

// ---------------------------------------------------------------------------
// fp32 -> bf16 bulk convert (n multiple of 4)
// ---------------------------------------------------------------------------
__global__ __launch_bounds__(256)
void cvt_k(const float* __restrict__ s, u16* __restrict__ d, int n)
{
    const int i = (blockIdx.x * 256 + threadIdx.x) * 4;
    if (i < n) {
        const float4 v = *(const float4*)(s + i);
        ushort4 o;
        o.x = f2b(v.x); o.y = f2b(v.y); o.z = f2b(v.z); o.w = f2b(v.w);
        *(ushort4*)(d + i) = o;
    }
}

// ---------------------------------------------------------------------------
// Embedding gather + cast: X[t*B+b, :] = bf16(emb[toks[t,b], :])
// ---------------------------------------------------------------------------
__global__ __launch_bounds__(128)
void gather_k(const int* __restrict__ toks, const float* __restrict__ emb,
              u16* __restrict__ X)
{
    const int row = blockIdx.x;
    const int tok = toks[row];
    const int c = threadIdx.x * 4;
    const float4 v = *(const float4*)(emb + (size_t)tok * EE + c);
    ushort4 o;
    o.x = f2b(v.x); o.y = f2b(v.y); o.z = f2b(v.z); o.w = f2b(v.w);
    *(ushort4*)(X + (size_t)row * EE + c) = o;
}

// ---------------------------------------------------------------------------
// init: h0ring slot0 <- bf16(h0 layer0); h1init <- bf16(h0 layer1); flags=0
// ---------------------------------------------------------------------------
__global__ __launch_bounds__(256)
void init_k(const float* __restrict__ h0in,
            u16* __restrict__ h0ring, u16* __restrict__ h1init,
            int* __restrict__ flags)
{
    const int i = blockIdx.x * 256 + threadIdx.x;   // [0, 2*BH)
    const u16 hb = f2b(h0in[i]);
    if (i < BH) h0ring[i] = hb;
    else        h1init[i - BH] = hb;
    if (i < 256) flags[i] = 0;
}

// ---------------------------------------------------------------------------
// Persistent fused 2-layer LSTM scan. 256 blocks (1/CU) x 1024 threads.
// Waves 0-7: layer 0 (x-part pre-barrier + W0h post). Waves 8-15: layer 1
// (W1x + W1h, both post-barrier). Weights LDS-resident. h-state flows
// through WRITE-ONCE rings (h0ring[129], H1all = h1 ring): readers use plain
// cached loads, writer visibility comes from per-block RELEASE flag stores
// (wbL2 + vmcnt drain) — no RMW barrier counter, no cache invalidation.
// Gate transpose (MFMA C-layout -> per-thread) is within-wave via LDS, so
// the only block barriers are post-poll and pre-arrive.
// ---------------------------------------------------------------------------
__global__ __launch_bounds__(1024, 1)
void scan_k(const float* __restrict__ Wih0, const float* __restrict__ Whh0,
            const float* __restrict__ Wih1, const float* __restrict__ Whh1,
            const float* __restrict__ bih0, const float* __restrict__ bhh0,
            const float* __restrict__ bih1, const float* __restrict__ bhh1,
            const float* __restrict__ c0in,
            const u16* __restrict__ Xb,
            u16* __restrict__ h0ring,   // 129 slots of BH (slot 0 = init)
            const u16* __restrict__ h1init,
            u16* __restrict__ H1all,    // T * BH (= h1 ring, slot t = step t)
            float* __restrict__ outT,   // d_out + T*BH: [hT (2BH), cT (2BH)]
            int* __restrict__ flags)    // 256 per-block phase flags
{
    extern __shared__ u16 lds[];
    u16* W0x = lds;                     // 16*4*16*8  =  8192 u16 (16 KB)
    u16* W0h = W0x + 16*4*16*8;         // 32*4*16*8  = 16384 u16 (32 KB)
    u16* W1x = W0h + 32*4*16*8;         //            = 16384 u16 (32 KB)
    u16* W1h = W1x + 32*4*16*8;         //            = 16384 u16 (32 KB)
    float* gst0 = (float*)(W1h + 32*4*16*8);  // 8*16*20 fp32 (10 KB)
    float* gst1 = gst0 + 8*16*20;             // 8*16*20 fp32 (10 KB)

    const int tid  = threadIdx.x;
    const int bk   = blockIdx.x;
    // swizzle: XCD (bk&7) owns a contiguous 128-col span
    const int j0   = (((bk & 7) << 5) | (bk >> 3)) * 4;
    const int lane = tid & 63;
    const int w    = tid >> 6;          // wave 0..15
    const int wg   = w & 7;             // m-tile within group
    const int grp  = w >> 3;            // 0 = layer0, 1 = layer1
    const int l15  = lane & 15, quad = lane >> 4;

    // ---- one-time: weights -> LDS (fp32 -> bf16, swizzled) ----
    auto loadW = [&](const float* src, int K, u16* dst) {
        const int ntup = (K / 32) * 4 * 16;
        for (int idx = tid; idx < ntup; idx += 1024) {
            const int n = idx & 15, q = (idx >> 4) & 3, kc = idx >> 6;
            const int col = ((n >> 2) * HH) + j0 + (n & 3);   // gate*H + j
            const float* sp = src + (size_t)col * K + kc * 32 + q * 8;
            const float4 v0 = *(const float4*)(sp);
            const float4 v1 = *(const float4*)(sp + 4);
            u16* dp = dst + (size_t)idx * 8;
            dp[0] = f2b(v0.x); dp[1] = f2b(v0.y); dp[2] = f2b(v0.z); dp[3] = f2b(v0.w);
            dp[4] = f2b(v1.x); dp[5] = f2b(v1.y); dp[6] = f2b(v1.z); dp[7] = f2b(v1.w);
        }
    };
    loadW(Wih0, EE, W0x);
    loadW(Whh0, HH, W0h);
    loadW(Wih1, HH, W1x);
    loadW(Whh1, HH, W1h);

    // pointwise thread mapping: tid<512 -> layer0 item, tid>=512 -> layer1
    const int t2   = tid & 511;
    const int prow = t2 >> 2;           // 0..127
    const int pjj  = t2 & 3;
    const int pj   = j0 + pjj;
    const int pw   = t2 >> 6;           // wave-in-group that owns gst row
    const int pr16 = prow & 15;

    const int lay = tid >> 9;           // 0 or 1
    float cs = c0in[(size_t)lay * BH + (size_t)prow * HH + pj];
    float bs[4];
    {
        const float* bihp = lay ? bih1 : bih0;
        const float* bhhp = lay ? bhh1 : bhh0;
        #pragma unroll
        for (int g = 0; g < 4; ++g) bs[g] = bihp[g * HH + pj] + bhhp[g * HH + pj];
    }

    __syncthreads();   // LDS weights ready

    const int arow = wg * 16 + l15;     // this lane's A-row (batch row)

    for (int p = 0; p <= TT; ++p) {
        f32x4 acc = (f32x4)0.0f;

        // (a) layer-0 waves: x-part, static data, runs before the barrier
        if (grp == 0 && p < TT) {
            const u16* ap = Xb + ((size_t)p * BB + arow) * EE + quad * 8;
            #pragma unroll 8
            for (int kc = 0; kc < 16; ++kc) {
                s8v a = *(const s8v*)(ap + kc * 32);
                s8v b = *(const s8v*)(W0x + ((size_t)(kc * 4 + quad) * 16 + l15) * 8);
                acc = MFMA(a, b, acc);
            }
        }

        // (b) wait: all 256 blocks finished phase p-1 (poll waves 8-11,
        //     which have no pre-barrier work)
        if (p > 0) {
            if (tid >= 512 && tid < 768) {
                while (__hip_atomic_load(&flags[tid - 512], __ATOMIC_RELAXED,
                                         __HIP_MEMORY_SCOPE_AGENT) < p) {
                    __builtin_amdgcn_s_sleep(1);
                }
            }
            __syncthreads();
            asm volatile("" ::: "memory");
        }

        // (c) h-dependent GEMMs (plain cached loads; L2-shared per XCD)
        const u16* h0p = h0ring + (size_t)p * BH;   // h0^{(p)}
        if (grp == 0) {
            if (p < TT) {
                const u16* ap = h0p + (size_t)arow * HH + quad * 8;
                #pragma unroll 8
                for (int kc = 0; kc < 32; ++kc) {
                    s8v a = *(const s8v*)(ap + kc * 32);
                    s8v b = *(const s8v*)(W0h + ((size_t)(kc * 4 + quad) * 16 + l15) * 8);
                    acc = MFMA(a, b, acc);
                }
            }
        } else if (p > 0) {
            const u16* ap0 = h0p + (size_t)arow * HH + quad * 8;
            const u16* h1p = (p == 1) ? h1init : (H1all + (size_t)(p - 2) * BH);
            const u16* ap1 = h1p + (size_t)arow * HH + quad * 8;
            #pragma unroll 8
            for (int kc = 0; kc < 32; ++kc) {
                s8v a0 = *(const s8v*)(ap0 + kc * 32);
                s8v b0 = *(const s8v*)(W1x + ((size_t)(kc * 4 + quad) * 16 + l15) * 8);
                acc = MFMA(a0, b0, acc);
                s8v a1 = *(const s8v*)(ap1 + kc * 32);
                s8v b1 = *(const s8v*)(W1h + ((size_t)(kc * 4 + quad) * 16 + l15) * 8);
                acc = MFMA(a1, b1, acc);
            }
        }

        // (d) gate transpose (within-wave LDS round trip) + pointwise
        {
            float* gw = (grp == 0) ? gst0 : gst1;
            #pragma unroll
            for (int r = 0; r < 4; ++r)
                gw[wg * 320 + (quad * 4 + r) * 20 + l15] = acc[r];
        }
        const bool active = lay ? (p > 0) : (p < TT);
        if (active) {
            const float* gr = (lay ? gst1 : gst0) + pw * 320 + pr16 * 20;
            const float gi = gr[0 + pjj]  + bs[0];
            const float gf = gr[4 + pjj]  + bs[1];
            const float gg = gr[8 + pjj]  + bs[2];
            const float go = gr[12 + pjj] + bs[3];
            cs = sigm(gf) * cs + sigm(gi) * tanh_(gg);
            const float h = sigm(go) * tanh_(cs);
            const u16 hb = f2b(h);
            if (lay == 0) {
                h0ring[(size_t)(p + 1) * BH + (size_t)prow * HH + pj] = hb;
                if (p == TT - 1) {
                    outT[(size_t)0 * BH + (size_t)prow * HH + pj] = h;    // hT l0
                    outT[(size_t)2 * BH + (size_t)prow * HH + pj] = cs;   // cT l0
                }
            } else {
                H1all[(size_t)(p - 1) * BH + (size_t)prow * HH + pj] = hb;
                if (p == TT) {
                    outT[(size_t)1 * BH + (size_t)prow * HH + pj] = h;    // hT l1
                    outT[(size_t)3 * BH + (size_t)prow * HH + pj] = cs;   // cT l1
                }
            }
        }

        // (e) arrive: drain all waves' stores (syncthreads -> vmcnt(0)),
        //     then one RELEASE flag store (wbL2 + wait + store). No RMW.
        if (p < TT) {
            __syncthreads();
            if (tid == 0) {
                __hip_atomic_store(&flags[bk], p + 1, __ATOMIC_RELEASE,
                                   __HIP_MEMORY_SCOPE_AGENT);
            }
        }
    }
}

// ---------------------------------------------------------------------------
// C[M,N] = act(A1 @ W[:, :K1]^T + A2 @ W[:, K1:]^T + bias)
// A/W bf16, bias fp32. Out: bf16 (Cb) or fp32 (Cf). Tile 64x64, 4 waves.
// ---------------------------------------------------------------------------
__global__ __launch_bounds__(256)
void gemm_bt_k(const u16* __restrict__ A1, int K1,
               const u16* __restrict__ A2, int K2,
               const u16* __restrict__ W, int ldw,
               const float* __restrict__ bias,
               u16* __restrict__ Cb, float* __restrict__ Cf,
               int N, int act)
{
    const int lane = threadIdx.x & 63;
    const int wave = threadIdx.x >> 6;
    const int l15 = lane & 15, quad = lane >> 4;
    const int n0 = blockIdx.x * 64;
    const int mrow = blockIdx.y * 64 + wave * 16;
    const int arow = mrow + l15;

    f32x4 acc[4];
    #pragma unroll
    for (int nt = 0; nt < 4; ++nt) acc[nt] = (f32x4)0.0f;

    const u16* wr0 = W + (size_t)(n0 + 0 * 16 + l15) * ldw + quad * 8;
    const u16* wr1 = W + (size_t)(n0 + 1 * 16 + l15) * ldw + quad * 8;
    const u16* wr2 = W + (size_t)(n0 + 2 * 16 + l15) * ldw + quad * 8;
    const u16* wr3 = W + (size_t)(n0 + 3 * 16 + l15) * ldw + quad * 8;

    {
        const u16* ap = A1 + (size_t)arow * K1 + quad * 8;
        #pragma unroll 4
        for (int kk = 0; kk < K1; kk += 32) {
            s8v a = *(const s8v*)(ap + kk);
            acc[0] = MFMA(a, *(const s8v*)(wr0 + kk), acc[0]);
            acc[1] = MFMA(a, *(const s8v*)(wr1 + kk), acc[1]);
            acc[2] = MFMA(a, *(const s8v*)(wr2 + kk), acc[2]);
            acc[3] = MFMA(a, *(const s8v*)(wr3 + kk), acc[3]);
        }
    }
    if (A2 != nullptr) {
        const u16* ap = A2 + (size_t)arow * K2 + quad * 8;
        #pragma unroll 4
        for (int kk = 0; kk < K2; kk += 32) {
            s8v a = *(const s8v*)(ap + kk);
            acc[0] = MFMA(a, *(const s8v*)(wr0 + K1 + kk), acc[0]);
            acc[1] = MFMA(a, *(const s8v*)(wr1 + K1 + kk), acc[1]);
            acc[2] = MFMA(a, *(const s8v*)(wr2 + K1 + kk), acc[2]);
            acc[3] = MFMA(a, *(const s8v*)(wr3 + K1 + kk), acc[3]);
        }
    }
    #pragma unroll
    for (int nt = 0; nt < 4; ++nt) {
        const int col = n0 + nt * 16 + l15;
        const float bv = bias[col];
        #pragma unroll
        for (int r = 0; r < 4; ++r) {
            const int row = mrow + quad * 4 + r;
            float v = acc[nt][r] + bv;
            if (act) v = tanh_(v);
            if (Cf) Cf[(size_t)row * N + col] = v;
            else    Cb[(size_t)row * N + col] = f2b(v);
        }
    }
}

// ---------------------------------------------------------------------------
// Attention: per block (b, 16-t chunk): scores = gamma @ ctx^T (MFMA, ctx
// cast on the fly), softmax over S in LDS, ct = w @ ctx (fp32 vector).
// ---------------------------------------------------------------------------
__global__ __launch_bounds__(256)
void attn_k(const u16* __restrict__ gamma, const float* __restrict__ ctx,
            u16* __restrict__ ctall)
{
    const int b = blockIdx.x;
    const int t0 = blockIdx.y * 16;
    const int tid = threadIdx.x;
    const int lane = tid & 63, wave = tid >> 6;
    const int l15 = lane & 15, quad = lane >> 4;

    __shared__ float sw[16 * SS];

    {
        f32x4 acc0 = (f32x4)0.0f, acc1 = (f32x4)0.0f;
        const u16*   ap  = gamma + ((size_t)(t0 + l15) * BB + b) * HH + quad * 8;
        const float* bp0 = ctx + ((size_t)b * SS + (wave * 32 + l15)) * HH + quad * 8;
        const float* bp1 = ctx + ((size_t)b * SS + (wave * 32 + 16 + l15)) * HH + quad * 8;
        for (int kk = 0; kk < HH; kk += 32) {
            s8v a = *(const s8v*)(ap + kk);
            float4 u0 = *(const float4*)(bp0 + kk);
            float4 u1 = *(const float4*)(bp0 + kk + 4);
            s8v bv;
            bv[0] = (short)f2b(u0.x); bv[1] = (short)f2b(u0.y);
            bv[2] = (short)f2b(u0.z); bv[3] = (short)f2b(u0.w);
            bv[4] = (short)f2b(u1.x); bv[5] = (short)f2b(u1.y);
            bv[6] = (short)f2b(u1.z); bv[7] = (short)f2b(u1.w);
            acc0 = MFMA(a, bv, acc0);
            float4 w0 = *(const float4*)(bp1 + kk);
            float4 w1 = *(const float4*)(bp1 + kk + 4);
            s8v cv;
            cv[0] = (short)f2b(w0.x); cv[1] = (short)f2b(w0.y);
            cv[2] = (short)f2b(w0.z); cv[3] = (short)f2b(w0.w);
            cv[4] = (short)f2b(w1.x); cv[5] = (short)f2b(w1.y);
            cv[6] = (short)f2b(w1.z); cv[7] = (short)f2b(w1.w);
            acc1 = MFMA(a, cv, acc1);
        }
        #pragma unroll
        for (int r = 0; r < 4; ++r) {
            const int trow = quad * 4 + r;
            sw[trow * SS + wave * 32 + l15] = acc0[r];
            sw[trow * SS + wave * 32 + 16 + l15] = acc1[r];
        }
    }
    __syncthreads();

    {
        const int row = tid >> 4, c0 = tid & 15;
        float e[8];
        float m = -1e30f;
        #pragma unroll
        for (int k = 0; k < 8; ++k) { e[k] = sw[row * SS + c0 + k * 16]; m = fmaxf(m, e[k]); }
        #pragma unroll
        for (int off = 8; off >= 1; off >>= 1) m = fmaxf(m, __shfl_xor(m, off));
        float s = 0.0f;
        #pragma unroll
        for (int k = 0; k < 8; ++k) { e[k] = __expf(e[k] - m); s += e[k]; }
        #pragma unroll
        for (int off = 8; off >= 1; off >>= 1) s += __shfl_xor(s, off);
        const float inv = 1.0f / s;
        #pragma unroll
        for (int k = 0; k < 8; ++k) sw[row * SS + c0 + k * 16] = e[k] * inv;
    }
    __syncthreads();

    {
        const int h0 = tid * 4;
        float a[16][4];
        #pragma unroll
        for (int t = 0; t < 16; ++t)
            #pragma unroll
            for (int q = 0; q < 4; ++q) a[t][q] = 0.0f;

        const float* cp = ctx + (size_t)b * SS * HH + h0;
        for (int s = 0; s < SS; ++s) {
            const float4 cv = *(const float4*)(cp + (size_t)s * HH);
            #pragma unroll
            for (int t = 0; t < 16; ++t) {
                const float wgt = sw[t * SS + s];
                a[t][0] += wgt * cv.x;
                a[t][1] += wgt * cv.y;
                a[t][2] += wgt * cv.z;
                a[t][3] += wgt * cv.w;
            }
        }
        #pragma unroll
        for (int t = 0; t < 16; ++t) {
            u16* op = ctall + ((size_t)(t0 + t) * BB + b) * HH + h0;
            #pragma unroll
            for (int q = 0; q < 4; ++q) op[q] = f2b(a[t][q]);
        }
    }
}

// ---------------------------------------------------------------------------
extern "C" void kernel_launch(void* const* d_in, const int* in_sizes, int n_in,
                              void* d_out, int out_size, void* d_ws, size_t ws_size,
                              hipStream_t stream)
{
    const int*   toks = (const int*)d_in[0];
    const float* h0in = (const float*)d_in[1];
    const float* c0in = (const float*)d_in[2];
    const float* ctx  = (const float*)d_in[3];
    const float* emb  = (const float*)d_in[4];
    const float* Wih0 = (const float*)d_in[5];
    const float* Whh0 = (const float*)d_in[6];
    const float* bih0 = (const float*)d_in[7];
    const float* bhh0 = (const float*)d_in[8];
    const float* Wih1 = (const float*)d_in[9];
    const float* Whh1 = (const float*)d_in[10];
    const float* bih1 = (const float*)d_in[11];
    const float* bhh1 = (const float*)d_in[12];
    const float* attW = (const float*)d_in[13];
    const float* attb = (const float*)d_in[14];
    const float* outW = (const float*)d_in[15];
    const float* outb = (const float*)d_in[16];

    // workspace layout (~125 MB)
    u16*   h0ring = (u16*)d_ws;                          // 129*BH (write-once ring)
    u16*   h1init = h0ring + (size_t)(TT + 1) * BH;      // BH
    int*   flags  = (int*)(h1init + BH);                 // 256 ints
    u16*   Xb     = (u16*)(flags + 256);                 // T*B*E
    u16*   H1all  = Xb + (size_t)TT * BB * EE;           // T*BH (h1 ring + tail input)
    u16*   gammaA = H1all + (size_t)TT * BH;             // T*BH
    u16*   attWb  = gammaA + (size_t)TT * BH;            // H*H
    u16*   outWb  = attWb + (size_t)HH * HH;             // H*2H
    u16*   ctall  = h0ring;   // alias: scan is done before attn_k writes here

    // one-time conversions for the batched tail
    cvt_k<<<dim3((HH * HH / 4 + 255) / 256), 256, 0, stream>>>(attW, attWb, HH * HH);
    cvt_k<<<dim3((2 * HH * HH / 4 + 255) / 256), 256, 0, stream>>>(outW, outWb, 2 * HH * HH);

    gather_k<<<dim3(TT * BB), 128, 0, stream>>>(toks, emb, Xb);
    init_k<<<dim3(2 * BH / 256), 256, 0, stream>>>(h0in, h0ring, h1init, flags);

    // persistent fused LSTM scan (writes H1all + hT/cT tail of d_out)
    float* outp = (float*)d_out;
    const int ldsBytes = (16*4*16*8 + 3 * 32*4*16*8) * 2 + 2 * 8*16*20 * 4;  // 135168
    hipFuncSetAttribute((const void*)scan_k,
                        hipFuncAttributeMaxDynamicSharedMemorySize, ldsBytes);
    scan_k<<<dim3(256), 1024, ldsBytes, stream>>>(
        Wih0, Whh0, Wih1, Whh1, bih0, bhh0, bih1, bhh1, c0in,
        Xb, h0ring, h1init, H1all, outp + (size_t)TT * BH, flags);

    // gamma = H1all @ attW^T + attb  (bf16 out)
    gemm_bt_k<<<dim3(HH / 64, (TT * BB) / 64), 256, 0, stream>>>(
        H1all, HH, nullptr, 0, attWb, HH, attb, gammaA, nullptr, HH, 0);

    // scores -> softmax -> ct
    attn_k<<<dim3(BB, TT / 16), 256, 0, stream>>>(gammaA, ctx, ctall);

    // out = tanh([ct, h1] @ outW^T + outb)  (fp32 out -> d_out)
    gemm_bt_k<<<dim3(HH / 64, (TT * BB) / 64), 256, 0, stream>>>(
        ctall, HH, H1all, HH, outWb, 2 * HH, outb, nullptr, outp, HH, 1);
}